// Round 1
// baseline (33.896 us; speedup 1.0000x reference)
//
#include <hip/hip_runtime.h>

#define BB 128
#define CC 3
#define HH 224
#define WW 224
#define KK 1000

// One thread per float4 along W. W/4 = 56 vec4 per row.
__global__ void cutmix_img_kernel(const float* __restrict__ img,
                                  const int* __restrict__ perm,
                                  const int* __restrict__ box,
                                  const int* __restrict__ xs,
                                  const int* __restrict__ ys,
                                  const int* __restrict__ keep,
                                  float* __restrict__ out) {
    const int WV = WW / 4;  // 56
    int tid = blockIdx.x * blockDim.x + threadIdx.x;
    int wv = tid % WV;
    int t  = tid / WV;
    int h  = t % HH;
    t      = t / HH;
    int c  = t % CC;
    int b  = t / CC;
    if (b >= BB) return;

    int w0 = wv * 4;
    size_t base = (((size_t)(b * CC + c) * HH) + h) * WW + w0;
    float4 v = *reinterpret_cast<const float4*>(img + base);

    int kp = keep[b];
    int x0 = xs[b];
    int bs = box[b];
    if (kp && h >= x0 && h < x0 + bs) {
        int y0 = ys[b];
        int y1 = y0 + bs;
        // does [w0, w0+4) overlap [y0, y1)?
        if (w0 + 4 > y0 && w0 < y1) {
            int pb = perm[b];
            size_t sbase = (((size_t)(pb * CC + c) * HH) + h) * WW + w0;
            float4 s = *reinterpret_cast<const float4*>(img + sbase);
            float* vp = &v.x;
            const float* sp = &s.x;
#pragma unroll
            for (int j = 0; j < 4; ++j) {
                int w = w0 + j;
                if (w >= y0 && w < y1) vp[j] = sp[j];
            }
        }
    }
    *reinterpret_cast<float4*>(out + base) = v;
}

// One thread per float4 of labels. K/4 = 250 vec4 per sample.
__global__ void cutmix_lab_kernel(const float* __restrict__ lab,
                                  const int* __restrict__ perm,
                                  const int* __restrict__ box,
                                  const int* __restrict__ keep,
                                  float* __restrict__ out) {
    const int KV = KK / 4;  // 250
    int tid = blockIdx.x * blockDim.x + threadIdx.x;
    int kv = tid % KV;
    int b  = tid / KV;
    if (b >= BB) return;

    size_t base = (size_t)b * KK + kv * 4;
    float4 l = *reinterpret_cast<const float4*>(lab + base);
    float4 o = l;
    if (keep[b]) {
        float bs = (float)box[b];
        float lam = 1.0f - bs * bs / (float)(HH * WW);
        float om = 1.0f - lam;
        int pb = perm[b];
        float4 s = *reinterpret_cast<const float4*>(lab + (size_t)pb * KK + kv * 4);
        o.x = lam * l.x + om * s.x;
        o.y = lam * l.y + om * s.y;
        o.z = lam * l.z + om * s.z;
        o.w = lam * l.w + om * s.w;
    }
    *reinterpret_cast<float4*>(out + base) = o;
}

extern "C" void kernel_launch(void* const* d_in, const int* in_sizes, int n_in,
                              void* d_out, int out_size, void* d_ws, size_t ws_size,
                              hipStream_t stream) {
    const float* images = (const float*)d_in[0];
    const float* labels = (const float*)d_in[1];
    const int* perm     = (const int*)d_in[2];
    const int* box      = (const int*)d_in[3];
    const int* xs       = (const int*)d_in[4];
    const int* ys       = (const int*)d_in[5];
    const int* keep     = (const int*)d_in[6];

    float* out_imgs = (float*)d_out;                                  // B*C*H*W floats
    float* out_labs = (float*)d_out + (size_t)BB * CC * HH * WW;      // B*K floats

    // images: B*C*H*(W/4) = 128*3*224*56 = 4,816,896 threads -> 18,816 blocks of 256 (exact)
    int img_threads = BB * CC * HH * (WW / 4);
    cutmix_img_kernel<<<img_threads / 256, 256, 0, stream>>>(
        images, perm, box, xs, ys, keep, out_imgs);

    // labels: B*(K/4) = 32,000 threads -> 125 blocks of 256 (exact)
    int lab_threads = BB * (KK / 4);
    cutmix_lab_kernel<<<lab_threads / 256, 256, 0, stream>>>(
        labels, perm, box, keep, out_labs);
}

// Round 2
// 30.002 us; speedup vs baseline: 1.1298x; 1.1298x over previous
//
#include <hip/hip_runtime.h>

#define BB 128
#define CC 3
#define HH 224
#define WW 224
#define KK 1000

#define IMG_VEC (BB * CC * HH * (WW / 4))   // 4,816,896 vec4 threads
#define LAB_VEC (BB * (KK / 4))             // 32,000 vec4 threads

__global__ __launch_bounds__(256) void cutmix_fused_kernel(
        const float* __restrict__ img,
        const float* __restrict__ lab,
        const int* __restrict__ perm,
        const int* __restrict__ box,
        const int* __restrict__ xs,
        const int* __restrict__ ys,
        const int* __restrict__ keep,
        float* __restrict__ out_img,
        float* __restrict__ out_lab) {
    int tid = blockIdx.x * blockDim.x + threadIdx.x;

    if (tid < IMG_VEC) {
        // ---- image path: one thread per float4 along W ----
        const int WV = WW / 4;  // 56
        int wv = tid % WV;
        int t  = tid / WV;
        int h  = t % HH;
        t      = t / HH;
        int c  = t % CC;
        int b  = t / CC;   // uniform within a block (49 blocks per (b,c) plane)

        int w0 = wv * 4;
        size_t base = (((size_t)(b * CC + c) * HH) + h) * WW + w0;

        int kp = keep[b];
        int x0 = xs[b];
        int bs = box[b];
        bool row_in = kp && ((unsigned)(h - x0) < (unsigned)bs);

        float4 v;
        if (row_in) {
            int y0 = ys[b];
            int y1 = y0 + bs;
            bool any  = (w0 + 4 > y0) && (w0 < y1);
            bool full = (w0 >= y0) && (w0 + 4 <= y1);
            int pb = perm[b];
            size_t sbase = (((size_t)(pb * CC + c) * HH) + h) * WW + w0;
            // single load from the selected source for full-inside / outside lanes
            size_t a = full ? sbase : base;
            v = *reinterpret_cast<const float4*>(img + a);
            if (any && !full) {
                // edge vec4: blend per lane (at most 2 such vec4 per row)
                float4 s = *reinterpret_cast<const float4*>(img + sbase);
                float* vp = &v.x;
                const float* sp = &s.x;
#pragma unroll
                for (int j = 0; j < 4; ++j) {
                    int w = w0 + j;
                    if (w >= y0 && w < y1) vp[j] = sp[j];
                }
            }
        } else {
            v = *reinterpret_cast<const float4*>(img + base);
        }
        *reinterpret_cast<float4*>(out_img + base) = v;
    } else {
        // ---- label path ----
        int idx = tid - IMG_VEC;
        if (idx >= LAB_VEC) return;
        const int KV = KK / 4;  // 250
        int kv = idx % KV;
        int b  = idx / KV;

        size_t base = (size_t)b * KK + kv * 4;
        float4 l = *reinterpret_cast<const float4*>(lab + base);
        float4 o = l;
        if (keep[b]) {
            float bsf = (float)box[b];
            float lam = 1.0f - bsf * bsf / (float)(HH * WW);
            float om = 1.0f - lam;
            int pb = perm[b];
            float4 s = *reinterpret_cast<const float4*>(lab + (size_t)pb * KK + kv * 4);
            o.x = lam * l.x + om * s.x;
            o.y = lam * l.y + om * s.y;
            o.z = lam * l.z + om * s.z;
            o.w = lam * l.w + om * s.w;
        }
        *reinterpret_cast<float4*>(out_lab + base) = o;
    }
}

extern "C" void kernel_launch(void* const* d_in, const int* in_sizes, int n_in,
                              void* d_out, int out_size, void* d_ws, size_t ws_size,
                              hipStream_t stream) {
    const float* images = (const float*)d_in[0];
    const float* labels = (const float*)d_in[1];
    const int* perm     = (const int*)d_in[2];
    const int* box      = (const int*)d_in[3];
    const int* xs       = (const int*)d_in[4];
    const int* ys       = (const int*)d_in[5];
    const int* keep     = (const int*)d_in[6];

    float* out_imgs = (float*)d_out;                                  // B*C*H*W floats
    float* out_labs = (float*)d_out + (size_t)BB * CC * HH * WW;      // B*K floats

    int total = IMG_VEC + LAB_VEC;            // 4,848,896
    int blocks = (total + 255) / 256;         // 18,941
    cutmix_fused_kernel<<<blocks, 256, 0, stream>>>(
        images, labels, perm, box, xs, ys, keep, out_imgs, out_labs);
}

// Round 3
// 29.744 us; speedup vs baseline: 1.1396x; 1.0087x over previous
//
#include <hip/hip_runtime.h>

#define BB 128
#define CC 3
#define HH 224
#define WW 224
#define KK 1000

#define WV (WW / 4)              // 56 vec4 per row
#define PLANE (HH * WV)          // 12544 vec4 per (b,c) plane
#define PER_B (CC * PLANE)       // 37632 vec4 per sample = 147 blocks * 256
#define IMG_BLOCKS (PER_B / 256) // 147
#define KV (KK / 4)              // 250 label vec4 per sample

__global__ __launch_bounds__(256) void cutmix_fused_kernel(
        const float* __restrict__ img,
        const float* __restrict__ lab,
        const int* __restrict__ perm,
        const int* __restrict__ box,
        const int* __restrict__ xs,
        const int* __restrict__ ys,
        const int* __restrict__ keep,
        float* __restrict__ out_img,
        float* __restrict__ out_lab) {
    const int b = blockIdx.y;          // scalar: all per-sample params -> s_load
    const int kp = keep[b];
    const int x0 = xs[b];
    const int bs = box[b];
    const int y0 = ys[b];
    const int pb = perm[b];

    if (blockIdx.x < IMG_BLOCKS) {
        // ---- image path: one thread per float4 ----
        int idx = blockIdx.x * 256 + threadIdx.x;   // [0, 37632)
        int c  = idx / PLANE;
        int r  = idx - c * PLANE;
        int h  = r / WV;
        int wv = r - h * WV;
        int w0 = wv * 4;

        size_t base = (((size_t)(b * CC + c) * HH) + h) * WW + w0;
        float4 v;
        bool row_in = kp && ((unsigned)(h - x0) < (unsigned)bs);
        if (row_in) {
            int y1 = y0 + bs;
            bool full = (w0 >= y0) && (w0 + 4 <= y1);
            size_t sbase = (((size_t)(pb * CC + c) * HH) + h) * WW + w0;
            v = *reinterpret_cast<const float4*>(img + (full ? sbase : base));
            if (!full && (w0 + 4 > y0) && (w0 < y1)) {
                // edge vec4 (at most 2 per row): blend per lane
                float4 s = *reinterpret_cast<const float4*>(img + sbase);
                float* vp = &v.x;
                const float* sp = &s.x;
#pragma unroll
                for (int j = 0; j < 4; ++j) {
                    int w = w0 + j;
                    if (w >= y0 && w < y1) vp[j] = sp[j];
                }
            }
        } else {
            v = *reinterpret_cast<const float4*>(img + base);
        }
        *reinterpret_cast<float4*>(out_img + base) = v;
    } else {
        // ---- label path: block x == IMG_BLOCKS, 250 active threads ----
        int kv = threadIdx.x;
        if (kv >= KV) return;
        size_t base = (size_t)b * KK + kv * 4;
        float4 l = *reinterpret_cast<const float4*>(lab + base);
        float4 o = l;
        if (kp) {
            float bsf = (float)bs;
            float lam = 1.0f - bsf * bsf / (float)(HH * WW);
            float om = 1.0f - lam;
            float4 s = *reinterpret_cast<const float4*>(lab + (size_t)pb * KK + kv * 4);
            o.x = lam * l.x + om * s.x;
            o.y = lam * l.y + om * s.y;
            o.z = lam * l.z + om * s.z;
            o.w = lam * l.w + om * s.w;
        }
        *reinterpret_cast<float4*>(out_lab + base) = o;
    }
}

extern "C" void kernel_launch(void* const* d_in, const int* in_sizes, int n_in,
                              void* d_out, int out_size, void* d_ws, size_t ws_size,
                              hipStream_t stream) {
    const float* images = (const float*)d_in[0];
    const float* labels = (const float*)d_in[1];
    const int* perm     = (const int*)d_in[2];
    const int* box      = (const int*)d_in[3];
    const int* xs       = (const int*)d_in[4];
    const int* ys       = (const int*)d_in[5];
    const int* keep     = (const int*)d_in[6];

    float* out_imgs = (float*)d_out;                                  // B*C*H*W floats
    float* out_labs = (float*)d_out + (size_t)BB * CC * HH * WW;      // B*K floats

    dim3 grid(IMG_BLOCKS + 1, BB);   // (148, 128)
    cutmix_fused_kernel<<<grid, 256, 0, stream>>>(
        images, labels, perm, box, xs, ys, keep, out_imgs, out_labs);
}